// Round 9
// baseline (357.164 us; speedup 1.0000x reference)
//
#include <hip/hip_runtime.h>
#include <hip/hip_bf16.h>

// Problem constants (fixed by reference)
static constexpr int NN = 20000;   // nodes
static constexpr int EE = 320000;  // edges (without self loops)
static constexpr int ET = EE + NN; // edges incl self loops = 340000
static constexpr int DD = 512;     // hidden dim
static constexpr int FIN = 128;    // input features
static constexpr int ETP_MAX = ET + 7 * NN; // 480000: padded-CSR worst case

typedef __attribute__((ext_vector_type(8))) short short8;           // 8 bf16 (4 VGPRs)
typedef __attribute__((ext_vector_type(8))) unsigned short ushort8; // 8 src ids (4 VGPRs)
typedef __attribute__((ext_vector_type(4))) float f32x4;            // MFMA C/D frag

// float -> bf16 (round to nearest even), raw ushort bits
__device__ __forceinline__ unsigned short f2bf(float f) {
    unsigned u = __float_as_uint(f);
    u += 0x7fffu + ((u >> 16) & 1u);
    return (unsigned short)(u >> 16);
}
__device__ __forceinline__ float bf2f(unsigned short b) {
    return __uint_as_float(((unsigned)b) << 16);
}

// async global->LDS DMA, 16 B per lane. LDS dest = wave-uniform base + lane*16.
__device__ __forceinline__ void async_copy16(short* lds, const unsigned short* g) {
    __builtin_amdgcn_global_load_lds(
        (const __attribute__((address_space(1))) unsigned int*)g,
        (__attribute__((address_space(3))) unsigned int*)lds,
        16, 0, 0);
}

// ---------- scan + degree-bucketed node permutation (single block) ----------
// row_ptr: exclusive scan of PADDED row length ((deg+1+7)&~7); pad slots keep
// csr_srcu = 0xFFFF (memset 0xFF) -> alpha = 0 exactly downstream.
// perm: counting-sort by clamped degree DESCENDING (wave sees 8 similar-degree
// nodes). Chain-split atomics (R4 fix); parallel 512-bin scan (R5 fix).
__global__ void scan_k(const int* __restrict__ deg, int* __restrict__ row_ptr,
                       int* __restrict__ perm) {
    __shared__ int part[1024];
    __shared__ int hist16[16][512]; // per-wave hist -> cross-wave exclusive bases
    __shared__ int hbase[512];      // bin totals -> global exclusive base (scanned)
    __shared__ int btot[512];       // bin totals (scan input copy)
    int t = threadIdx.x;
    int wv = t >> 6;
    for (int k = t; k < 16 * 512; k += 1024) ((int*)hist16)[k] = 0;
    __syncthreads();
    const int CH = (NN + 1023) / 1024; // 20
    int start = t * CH;
    int end = min(start + CH, NN);
    int dl[CH]; // true length cache (one global pass)
    int s = 0;
    for (int i = start; i < end; ++i) {
        int d = deg[i] + 1;
        dl[i - start] = d;
        s += (d + 7) & ~7; // padded length
        atomicAdd(&hist16[wv][min(d, 511)], 1); // intra-wave chains only
    }
    part[t] = s;
    __syncthreads();
    // cross-wave per-bin exclusive prefix (atomic-free); totals in btot/hbase
    if (t < 512) {
        int base = 0;
#pragma unroll
        for (int w = 0; w < 16; ++w) { int c = hist16[w][t]; hist16[w][t] = base; base += c; }
        btot[t] = base;
        hbase[t] = base;
    }
    __syncthreads();
    // parallel inclusive scan of hbase[0..511] (Hillis-Steele)
    for (int off = 1; off < 512; off <<= 1) {
        int v = 0;
        if (t < 512 && t >= off) v = hbase[t - off];
        __syncthreads();
        if (t < 512) hbase[t] += v;
        __syncthreads();
    }
    if (t < 512) hbase[t] -= btot[t]; // exclusive
    // 1024-way prefix scan of per-thread padded sums
    for (int off = 1; off < 1024; off <<= 1) {
        int v = 0;
        if (t >= off) v = part[t - off];
        __syncthreads();
        part[t] += v;
        __syncthreads();
    }
    int base = (t == 0) ? 0 : part[t - 1];
    for (int i = start; i < end; ++i) { row_ptr[i] = base; base += (dl[i - start] + 7) & ~7; }
    if (t == 1023) row_ptr[NN] = part[1023]; // total padded slot count
    // scatter: pos = global bin base + cross-wave base + intra-wave rank
    for (int i = start; i < end; ++i) {
        int d = min(dl[i - start], 511);
        int r = atomicAdd(&hist16[wv][d], 1);
        int pos = hbase[d] + r;
        perm[NN - 1 - pos] = i; // descending degree order
    }
}

// ---------- merged prep: weight transpose + x->bf16 (float4) + count_deg ----------
static constexpr int TBLK = 208;                // transpose tile blocks (16 + 3*64)
static constexpr int SZ_X4 = NN * FIN / 4;      // 640,000 float4 units
static constexpr int XCB = (SZ_X4 + 255) / 256; // 2500 x-conversion blocks
static constexpr int CDB = (EE + 255) / 256;    // 1250 count-deg blocks
__global__ __launch_bounds__(256) void prep_all_k(
    const float* __restrict__ x, const float* __restrict__ W1,
    const float* __restrict__ fc1, const float* __restrict__ W2,
    const float* __restrict__ fc2,
    unsigned short* __restrict__ xb, unsigned short* __restrict__ W1t,
    unsigned short* __restrict__ fc1t, unsigned short* __restrict__ W2t,
    unsigned short* __restrict__ fc2t,
    const void* __restrict__ ei, int is64, int* __restrict__ deg) {
    int b = blockIdx.x;
    if (b < CDB) { // fused in-degree count (real edges)
        int i = b * 256 + threadIdx.x;
        if (i < EE) {
            int d = is64 ? (int)((const long long*)ei)[EE + i] : ((const int*)ei)[EE + i];
            atomicAdd(&deg[d], 1);
        }
        return;
    }
    b -= CDB;
    if (b < TBLK) { // 64x64 transpose tiles, coalesced reads AND writes
        __shared__ unsigned short tile[64][65];
        const float* src; unsigned short* dst; int rows, cols;
        if (b < 16)       { src = W1;  dst = W1t;  rows = FIN; cols = DD; }
        else if (b < 80)  { b -= 16;  src = fc1; dst = fc1t; rows = DD; cols = DD; }
        else if (b < 144) { b -= 80;  src = W2;  dst = W2t;  rows = DD; cols = DD; }
        else              { b -= 144; src = fc2; dst = fc2t; rows = DD; cols = DD; }
        int tc = cols / 64;
        int r0 = (b / tc) * 64, c0 = (b % tc) * 64;
        int t = threadIdx.x, lr = t >> 6, lc = t & 63;
#pragma unroll
        for (int p = 0; p < 16; ++p) {
            int r = lr + p * 4;
            tile[r][lc] = f2bf(src[(size_t)(r0 + r) * cols + c0 + lc]);
        }
        __syncthreads();
#pragma unroll
        for (int p = 0; p < 16; ++p) {
            int r = lr + p * 4; // output row = source col
            dst[(size_t)(c0 + r) * rows + r0 + lc] = tile[lc][r];
        }
        return;
    }
    int i = (b - TBLK) * 256 + threadIdx.x; // float4-granular x conversion
    if (i < SZ_X4) {
        float4 v = ((const float4*)x)[i];
        unsigned short o[4] = {f2bf(v.x), f2bf(v.y), f2bf(v.z), f2bf(v.w)};
        *(unsigned long long*)(xb + (size_t)i * 4) = *(const unsigned long long*)o;
    }
}

// ---------- bf16 MFMA GEMM: Cb[M,Nc] = bf16( A[M,K] @ Bt[Nc,K]^T (+bias)(+relu) ) ----------
// 128x128 tile, BK=64 (two 32-elem half-tiles), 256 threads = 4 waves (2x2),
// each wave 4x4 tiles of 16x16x32. Staging via async global_load_lds (16 B/lane).
// STATS: fused BN sum/sumsq. ALS: fused attention logits.
// FILLEX: blocks >= 640 run the (independent) fill_csr scatter instead.
template <int RELU, int HASBIAS, int STATS, int ALS, int H, int FILLEX>
__global__ __launch_bounds__(256) void gemm_bf16(const unsigned short* __restrict__ A,
                                                 const unsigned short* __restrict__ Bt,
                                                 const float* __restrict__ bias,
                                                 unsigned short* __restrict__ Cb,
                                                 float* __restrict__ bnstat,
                                                 const float* __restrict__ avs,
                                                 const float* __restrict__ avd,
                                                 float* __restrict__ al_s,
                                                 float* __restrict__ al_d,
                                                 int M, int Nc, int K,
                                                 const void* __restrict__ ei, int is64,
                                                 const int* __restrict__ rp,
                                                 int* __restrict__ cursor,
                                                 unsigned short* __restrict__ csr_srcu,
                                                 int* __restrict__ csr_dst) {
    int id = blockIdx.x;
    if (FILLEX && id >= 640) { // fused fill_csr (independent of GEMM work)
        int e = (id - 640) * 256 + threadIdx.x;
        if (e >= ET) return;
        int s, d;
        if (e < EE) {
            if (is64) {
                const long long* p = (const long long*)ei;
                s = (int)p[e]; d = (int)p[EE + e];
            } else {
                const int* p = (const int*)ei;
                s = p[e]; d = p[EE + e];
            }
        } else {
            s = d = e - EE;
        }
        int pos = atomicAdd(&cursor[d], 1);
        int slot = rp[d] + pos; // rows padded to x8; real slots at row start
        csr_srcu[slot] = (unsigned short)s; // NN < 65536; pads stay 0xFFFF
        csr_dst[slot] = d;
        return;
    }
    int bm = ((id >> 5) << 3) + (id & 7); // 0..159
    int bn = (id >> 3) & 3;               // 0..3
    int m0 = bm * 128, n0 = bn * 128;
    if (m0 >= M) return; // padded m-tiles: whole block exits (no barrier executed)

    __shared__ short As0[128 * 32], As1[128 * 32]; // k-halves, 8 KB each
    __shared__ short Bs0[128 * 32], Bs1[128 * 32];
    int t = threadIdx.x;
    int lane = t & 63, w = t >> 6;
    int wm = w & 1, wn = w >> 1;           // wave quadrant (2x2 of 64x64)
    int quad = lane >> 4, mr = lane & 15;  // MFMA fragment indices
    int lrow = lane >> 2;                  // staging: row within 16-row group
    int lcol = (lane & 3) * 8;             // staging: elem offset within 32-elem half-row

    const unsigned short* Ag0 = A + (size_t)(m0 + w * 32 + lrow) * K + lcol;
    const unsigned short* Ag1 = A + (size_t)(m0 + w * 32 + 16 + lrow) * K + lcol;
    const unsigned short* Bg0 = Bt + (size_t)(n0 + w * 32 + lrow) * K + lcol;
    const unsigned short* Bg1 = Bt + (size_t)(n0 + w * 32 + 16 + lrow) * K + lcol;
    short* Al[2][2] = {{&As0[(w * 32) * 32], &As0[(w * 32 + 16) * 32]},
                       {&As1[(w * 32) * 32], &As1[(w * 32 + 16) * 32]}};
    short* Bl[2][2] = {{&Bs0[(w * 32) * 32], &Bs0[(w * 32 + 16) * 32]},
                       {&Bs1[(w * 32) * 32], &Bs1[(w * 32 + 16) * 32]}};

    f32x4 zero = {0.f, 0.f, 0.f, 0.f};
    f32x4 acc[4][4];
#pragma unroll
    for (int i = 0; i < 4; ++i)
#pragma unroll
        for (int j = 0; j < 4; ++j) acc[i][j] = zero;

    for (int k0 = 0; k0 < K; k0 += 64) {
        async_copy16(Al[0][0], Ag0 + k0);
        async_copy16(Al[1][0], Ag0 + k0 + 32);
        async_copy16(Al[0][1], Ag1 + k0);
        async_copy16(Al[1][1], Ag1 + k0 + 32);
        async_copy16(Bl[0][0], Bg0 + k0);
        async_copy16(Bl[1][0], Bg0 + k0 + 32);
        async_copy16(Bl[0][1], Bg1 + k0);
        async_copy16(Bl[1][1], Bg1 + k0 + 32);
        __syncthreads(); // drains vmcnt(0): DMA data landed in LDS
#pragma unroll
        for (int kp = 0; kp < 2; ++kp) {
            const short* Sa = kp ? As1 : As0;
            const short* Sb = kp ? Bs1 : Bs0;
            short8 af[4], bfr[4];
#pragma unroll
            for (int i = 0; i < 4; ++i) {
                af[i]  = *(const short8*)(&Sa[(wm * 64 + i * 16 + mr) * 32 + quad * 8]);
                bfr[i] = *(const short8*)(&Sb[(wn * 64 + i * 16 + mr) * 32 + quad * 8]);
            }
#pragma unroll
            for (int i = 0; i < 4; ++i)
#pragma unroll
                for (int j = 0; j < 4; ++j)
                    acc[i][j] = __builtin_amdgcn_mfma_f32_16x16x32_bf16(af[i], bfr[j], acc[i][j], 0, 0, 0);
        }
        __syncthreads(); // all waves done reading before next DMA overwrites
    }

    // epilogue: C/D layout col = lane&15, row = (lane>>4)*4 + reg  [m89/m91]
    float as_j[4], ad_j[4];
    if (ALS) {
#pragma unroll
        for (int j = 0; j < 4; ++j) {
            int n = n0 + wn * 64 + j * 16 + mr;
            as_j[j] = avs[n]; // a[H][C] flat == global col index for both H=8 and H=1
            ad_j[j] = avd[n];
        }
    }
    const int head = (H == 8) ? ((n0 + wn * 64) >> 6) : 0;
    float sj[4] = {0.f, 0.f, 0.f, 0.f}, qj[4] = {0.f, 0.f, 0.f, 0.f};
#pragma unroll
    for (int i = 0; i < 4; ++i) {
        int mb = m0 + wm * 64 + i * 16 + quad * 4;
#pragma unroll
        for (int r = 0; r < 4; ++r) {
            int m = mb + r;               // uniform across the 16 mr-lanes
            bool valid = (m < M);
            float ps = 0.f, pd = 0.f;
#pragma unroll
            for (int j = 0; j < 4; ++j) {
                int n = n0 + wn * 64 + j * 16 + mr;
                float v = acc[i][j][r];
                if (HASBIAS) v += bias[n];
                if (RELU) v = fmaxf(v, 0.f);
                unsigned short hb = f2bf(v);
                if (valid) Cb[(size_t)m * Nc + n] = hb;
                if (ALS) {
                    float vv = bf2f(hb); // match downstream bf16 read
                    ps += as_j[j] * vv;
                    pd += ad_j[j] * vv;
                }
                if (STATS && valid) { sj[j] += v; qj[j] += v * v; }
            }
            if (ALS) {
                ps += __shfl_xor(ps, 1); pd += __shfl_xor(pd, 1);
                ps += __shfl_xor(ps, 2); pd += __shfl_xor(pd, 2);
                ps += __shfl_xor(ps, 4); pd += __shfl_xor(pd, 4);
                ps += __shfl_xor(ps, 8); pd += __shfl_xor(pd, 8);
                if (mr == 0 && valid) {
                    if (H == 8) { al_s[m * 8 + head] = ps; al_d[m * 8 + head] = pd; }
                    else        { atomicAdd(&al_s[m], ps); atomicAdd(&al_d[m], pd); }
                }
            }
        }
    }
    if (STATS) {
#pragma unroll
        for (int j = 0; j < 4; ++j) {
            float s = sj[j], q = qj[j];
            s += __shfl_xor(s, 16); q += __shfl_xor(q, 16);
            s += __shfl_xor(s, 32); q += __shfl_xor(q, 32);
            if (lane < 16) { // quad==0 holds the 4-row-group total for this column
                int n = n0 + wn * 64 + j * 16 + mr;
                atomicAdd(&bnstat[n], s);
                atomicAdd(&bnstat[512 + n], q);
            }
        }
    }
}

// ---------- alpha precompute for LAYER 2 only (H=1: all 8 slices share alpha) ----------
// Pad slots (csr_srcu == 0xFFFF) get alpha = 0.0 -> exact +0.0 downstream.
__global__ __launch_bounds__(256) void alpha2_k(const float* __restrict__ al_s,
                                                const float* __restrict__ al_d,
                                                const unsigned short* __restrict__ csr_srcu,
                                                const int* __restrict__ csr_dst,
                                                const int* __restrict__ row_ptr,
                                                float* __restrict__ al) {
    int p = blockIdx.x * blockDim.x + threadIdx.x;
    if (p >= row_ptr[NN]) return;
    unsigned sn = csr_srcu[p];
    if (sn == 0xFFFFu) { al[p] = 0.f; return; }
    int d = csr_dst[p];
    float xx = al_s[sn] + al_d[d];
    al[p] = __expf(fmaxf(xx, 0.2f * xx));
}

// ---------- gather-aggregate v8: software-pipelined h-loads (R9) ----------
// 8 nodes x 8 lanes per wave; perm gives 8 similar-degree nodes/wave; rows padded
// to x8 (pad alpha = 0 exactly). slice = blockIdx&7 -> XCD pin (proven R2).
// R8 post-mortem: 42 us each, VALUBusy 44%, latency-bound -- h loads were issued
// at the top of each iteration and waited on immediately. Now: A/B double-buffer,
// PREP(bb) issues sv + 8 h-loads + (H=8) 8 raw al_s loads; the expf/pad-select is
// DEFERRED to STAGE (one batch later), so every load has a full FMA block (~280cy)
// in flight before use. Pad slots: xal = -inf -> exp = 0 exactly (bit-identical
// accumulation order vs R8). Static indexing throughout (rule #20).
template <int H>
__global__ __launch_bounds__(256) void gat_gather_k(const unsigned short* __restrict__ hb,
                                                    const unsigned short* __restrict__ srcu,
                                                    const float* __restrict__ alp, // H=8: al_s [NN][8]; H=1: alpha plane
                                                    const float* __restrict__ ald_t, // H=8: al_d [NN][8]; H=1: unused
                                                    const int* __restrict__ row_ptr,
                                                    const int* __restrict__ perm,
                                                    const float* __restrict__ bias,
                                                    unsigned short* __restrict__ outb) {
    int b = blockIdx.x;
    int s = b & 7;                  // col-slice 0..7 == XCD id == head (H=8)
    int g = b >> 3;                 // node group 0..624
    int t = threadIdx.x;
    int w = t >> 6, lane = t & 63;
    int grp = lane >> 3, cg = lane & 7;
    int n = perm[g * 32 + w * 8 + grp]; // NN = 625*32
    int col = s * 64 + cg * 8;      // this lane's 8 columns
    const char* hbase = (const char*)hb + col * 2; // + (src<<10) bytes
    int beg = row_ptr[n];
    int nb = (row_ptr[n + 1] - beg) >> 3; // exact batch count (padded rows), >= 1
    const float* asp = alp + s;     // H=8: head-s logit column of al_s
    float ald = (H == 8) ? ald_t[n * 8 + s] : 0.f;
    const float NEGINF = __int_as_float(0xff800000);

    float acc[8] = {0.f, 0.f, 0.f, 0.f, 0.f, 0.f, 0.f, 0.f};
    float psum = 0.f;

    // PREP: issue all loads for batch bb into (xal, h). No consumption of the
    // issued loads here except sv (address dependency) -- expf deferred to STAGE.
    auto PREP = [&](int bb, float (&xal)[8], short8 (&h)[8]) {
        int p0 = beg + bb * 8;
        ushort8 sv = *(const ushort8*)(srcu + p0); // 16B aligned (beg%8==0)
        if (H == 1) {
            float4 a0 = *(const float4*)(alp + p0);
            float4 a1 = *(const float4*)(alp + p0 + 4);
            xal[0] = a0.x; xal[1] = a0.y; xal[2] = a0.z; xal[3] = a0.w;
            xal[4] = a1.x; xal[5] = a1.y; xal[6] = a1.z; xal[7] = a1.w;
#pragma unroll
            for (int u = 0; u < 8; ++u) {
                unsigned sa = (sv[u] == 0xFFFFu) ? 0u : (unsigned)sv[u];
                h[u] = *(const short8*)(hbase + ((size_t)sa << 10));
            }
        } else {
#pragma unroll
            for (int u = 0; u < 8; ++u) {
                unsigned snv = sv[u];
                unsigned sa = (snv == 0xFFFFu) ? 0u : snv;
                float xv = asp[(size_t)sa * 8];           // raw logit (scattered, L2)
                xal[u] = (snv == 0xFFFFu) ? NEGINF : xv;  // pad -> exp(-inf)=0 exactly
                h[u] = *(const short8*)(hbase + ((size_t)sa << 10));
            }
        }
    };
    // STAGE: consume batch (loads have been in flight one full batch)
    auto STAGE = [&](const float (&xal)[8], const short8 (&h)[8]) {
        float av[8];
#pragma unroll
        for (int u = 0; u < 8; ++u) {
            if (H == 8) {
                float xx = xal[u] + ald;
                av[u] = __expf(fmaxf(xx, 0.2f * xx));
            } else {
                av[u] = xal[u];
            }
            psum += av[u];
        }
#pragma unroll
        for (int u = 0; u < 8; ++u)
#pragma unroll
            for (int j = 0; j < 8; ++j)
                acc[j] = fmaf(av[u], bf2f((unsigned short)h[u][j]), acc[j]);
    };

    float xalA[8], xalB[8];
    short8 hA[8], hB[8];
    PREP(0, xalA, hA);
    if (nb > 1) PREP(1, xalB, hB);
    for (int bb = 0; bb < nb; bb += 2) {
        STAGE(xalA, hA);                                  // batch bb
        if (bb + 2 < nb) PREP(bb + 2, xalA, hA);          // refill A (used next iter)
        if (bb + 1 >= nb) break;
        STAGE(xalB, hB);                                  // batch bb+1
        if (bb + 3 < nb) PREP(bb + 3, xalB, hB);          // refill B
    }

    float inv = 1.0f / psum;
    float4 b0 = *(const float4*)(bias + col);
    float4 b1 = *(const float4*)(bias + col + 4);
    float bz[8] = {b0.x, b0.y, b0.z, b0.w, b1.x, b1.y, b1.z, b1.w};
    unsigned short ov[8];
#pragma unroll
    for (int j = 0; j < 8; ++j) ov[j] = f2bf(acc[j] * inv + bz[j]);
    *(int4*)(outb + (size_t)n * DD + col) = *(const int4*)ov;
}

// ---------- fold BN1 into W2: W2t[n][k] *= sc[k] (in place); bias2[n] = sum_k sh[k]*W2t[n][k] ----------
__global__ __launch_bounds__(256) void fold1_k(const float* __restrict__ stat,
                                               const float* __restrict__ g,
                                               const float* __restrict__ be,
                                               unsigned short* __restrict__ W2t,
                                               float* __restrict__ bias2) {
    int t = threadIdx.x;
    int n = blockIdx.x * 4 + (t >> 6); // 128 blocks -> n in [0,512)
    int lane = t & 63;
    float pb = 0.f;
#pragma unroll
    for (int j = 0; j < 8; ++j) {
        int k = lane * 8 + j;
        float mean = stat[k] * (1.0f / NN);
        float var = stat[512 + k] * (1.0f / NN) - mean * mean;
        float sc = g[k] * rsqrtf(var + 1e-5f);
        float sh = be[k] - mean * sc;
        float wv = bf2f(W2t[n * DD + k]);
        W2t[n * DD + k] = f2bf(sc * wv);
        pb += sh * wv;
    }
    for (int off = 32; off; off >>= 1) pb += __shfl_down(pb, off);
    if (lane == 0) bias2[n] = pb;
}

// ---------- final linear with BN2 fold fused per-block ----------
// Each block (4 waves = 4 nodes) first cooperatively folds BN2 into LDS
// (w01[c] = sc_c * lin_w[c][.]; k0/k1 = sum of const terms), then each wave
// does the 512-dot for its node. stat/g/be/lw are 8 KB total -> L2-hot.
__global__ __launch_bounds__(256) void final_linear(const unsigned short* __restrict__ xb,
                                                    const float* __restrict__ stat,
                                                    const float* __restrict__ g,
                                                    const float* __restrict__ be,
                                                    const float* __restrict__ lw,
                                                    const float* __restrict__ lb,
                                                    float* __restrict__ out) {
    __shared__ float w01[1024];
    __shared__ float red[512];
    int t = threadIdx.x;
    float rr0 = 0.f, rr1 = 0.f;
#pragma unroll
    for (int q = 0; q < 2; ++q) {
        int c = t * 2 + q; // 0..511
        float mean = stat[c] * (1.0f / NN);
        float var = stat[512 + c] * (1.0f / NN) - mean * mean;
        float sc = g[c] * rsqrtf(var + 1e-5f);
        float sh = be[c] - mean * sc;
        float w0 = lw[2 * c], w1 = lw[2 * c + 1];
        w01[2 * c] = sc * w0;
        w01[2 * c + 1] = sc * w1;
        rr0 = fmaf(sh, w0, rr0);
        rr1 = fmaf(sh, w1, rr1);
    }
    red[t] = rr0;
    red[256 + t] = rr1;
    __syncthreads();
    for (int off = 128; off; off >>= 1) {
        if (t < off) { red[t] += red[t + off]; red[256 + t] += red[256 + t + off]; }
        __syncthreads();
    }
    float k0 = red[0] + lb[0], k1 = red[256] + lb[1];

    int wave = blockIdx.x * 4 + (t >> 6);
    int lane = t & 63;
    short8 hv = *(const short8*)(xb + (size_t)wave * DD + lane * 8);
    float p0 = 0.f, p1 = 0.f;
#pragma unroll
    for (int j = 0; j < 8; ++j) {
        int c = lane * 8 + j;
        float h = bf2f((unsigned short)hv[j]);
        p0 = fmaf(h, w01[2 * c], p0);
        p1 = fmaf(h, w01[2 * c + 1], p1);
    }
    for (int off = 32; off; off >>= 1) {
        p0 += __shfl_down(p0, off);
        p1 += __shfl_down(p1, off);
    }
    if (lane == 0) {
        out[wave * 2 + 0] = fmaxf(p0 + k0, 0.f);
        out[wave * 2 + 1] = fmaxf(p1 + k1, 0.f);
    }
}

extern "C" void kernel_launch(void* const* d_in, const int* in_sizes, int n_in,
                              void* d_out, int out_size, void* d_ws, size_t ws_size,
                              hipStream_t stream) {
    const float* x     = (const float*)d_in[0];
    const void*  ei    = d_in[1];
    const float* W1    = (const float*)d_in[2];
    const float* a1s   = (const float*)d_in[3];
    const float* a1d   = (const float*)d_in[4];
    const float* b1    = (const float*)d_in[5];
    const float* W2    = (const float*)d_in[6];
    const float* a2s   = (const float*)d_in[7];
    const float* a2d   = (const float*)d_in[8];
    const float* b2    = (const float*)d_in[9];
    const float* fc1_w = (const float*)d_in[10];
    const float* fc1_b = (const float*)d_in[11];
    const float* g1    = (const float*)d_in[12];
    const float* be1   = (const float*)d_in[13];
    const float* fc2_w = (const float*)d_in[14];
    const float* fc2_b = (const float*)d_in[15];
    const float* g2    = (const float*)d_in[16];
    const float* be2   = (const float*)d_in[17];
    const float* lin_w = (const float*)d_in[18];
    const float* lin_b = (const float*)d_in[19];
    float* out = (float*)d_out;

    // workspace carve-up (256B aligned)
    char* ws = (char*)d_ws;
    auto alloc = [&](size_t bytes) {
        void* p = (void*)ws;
        ws += (bytes + 255) & ~size_t(255);
        return p;
    };
    unsigned short* h_bf    = (unsigned short*)alloc((size_t)NN * DD * 2); // ping
    unsigned short* act_bf  = (unsigned short*)alloc((size_t)NN * DD * 2); // pong
    unsigned short* W1t     = (unsigned short*)alloc((size_t)DD * FIN * 2);
    unsigned short* fc1t    = (unsigned short*)alloc((size_t)DD * DD * 2);
    unsigned short* W2t     = (unsigned short*)alloc((size_t)DD * DD * 2);
    unsigned short* fc2t    = (unsigned short*)alloc((size_t)DD * DD * 2);
    float*          al_s    = (float*)alloc((size_t)NN * 8 * 4);           // layer-1 logits (H=8)
    float*          al_d    = (float*)alloc((size_t)NN * 8 * 4);
    int*            row_ptr = (int*)alloc((size_t)(NN + 1) * 4);
    int*            csr_dst = (int*)alloc((size_t)ETP_MAX * 4);            // real slots only (read behind pad check)
    int*            perm    = (int*)alloc((size_t)NN * 4);                 // degree-sorted nodes
    float*          bias2f  = (float*)alloc(512 * 4);                      // BN1-fold bias for W2 GEMM
    float*          ea_al   = (float*)alloc((size_t)ETP_MAX * 4);          // layer-2 alpha plane
    // zero-region: deg + cursor + bnstatA/B + al_s2 + al_d2 (ONE memset)
    int*            deg     = (int*)alloc((size_t)(4 * NN + 2048) * 4);
    int*            cursor  = deg + NN;
    float*          bnstatA = (float*)(deg + 2 * NN);
    float*          bnstatB = bnstatA + 1024;
    float*          al_s2   = bnstatA + 2048;
    float*          al_d2   = al_s2 + NN;
    // 0xFF-region: csr_srcu (pad slots stay 0xFFFF -> alpha 0 downstream)
    unsigned short* csr_srcu = (unsigned short*)alloc((size_t)ETP_MAX * 2);

    // --- host-side edge dtype detection: in_sizes[1] is byte size of edge_index ---
    const int is64 = (in_sizes[1] >= (int)(2u * EE * 8u)) ? 1 : 0;

    // --- init via graph-capturable async memsets (2 total) ---
    hipMemsetAsync(deg, 0, (size_t)(4 * NN + 2048) * 4, stream);
    hipMemsetAsync(csr_srcu, 0xFF, (size_t)ETP_MAX * 2, stream);

    // --- merged: count_deg + weight transpose + x conversion (one launch) ---
    unsigned short* x_bf = act_bf; // consumed by GEMM1 before gat_gather_k overwrites
    const int prep_blocks = CDB + TBLK + XCB;
    prep_all_k<<<prep_blocks, 256, 0, stream>>>(x, W1, fc1_w, W2, fc2_w,
                                                x_bf, W1t, fc1t, W2t, fc2t,
                                                ei, is64, deg);
    // padded row_ptr + degree-bucketed perm (single block, chain-split atomics)
    scan_k<<<1, 1024, 0, stream>>>(deg, row_ptr, perm);

    const int GB = 640;              // GEMM blocks: 160 padded m-tiles x 4 n-tiles
    const int FB = (ET + 255) / 256; // fused fill_csr blocks (real slots only)
    const int GGB = 8 * (NN / 32);   // gather: 8 col-slices x 625 node-groups = 5000
    const int AB = (ETP_MAX + 255) / 256; // alpha2 blocks cover padded worst case

    // ---------------- Layer 1: GATConv(128 -> 8 x 64) ----------------
    // h1 = x @ W1 (bf16 out) + fused logits + fused fill_csr (independent blocks)
    gemm_bf16<0, 0, 0, 1, 8, 1><<<GB + FB, 256, 0, stream>>>(
        x_bf, W1t, nullptr, h_bf, nullptr, a1s, a1d, al_s, al_d, NN, DD, FIN,
        ei, is64, row_ptr, cursor, csr_srcu, csr_dst);
    // gather with FUSED alpha (head == slice; no alpha1 kernel), pipelined loads
    gat_gather_k<8><<<GGB, 256, 0, stream>>>(h_bf, csr_srcu, al_s, al_d, row_ptr, perm, b1, act_bf);
    // r1 = relu(agg1 @ fc1 + b) (bf16 out) + fused BN stats
    gemm_bf16<1, 1, 1, 0, 8, 0><<<GB, 256, 0, stream>>>(
        act_bf, fc1t, fc1_b, h_bf, bnstatA, nullptr, nullptr, nullptr, nullptr, NN, DD, DD,
        nullptr, 0, nullptr, nullptr, nullptr, nullptr);
    // fold BN1 into W2 weights + bias
    fold1_k<<<128, 256, 0, stream>>>(bnstatA, g1, be1, W2t, bias2f);

    // ---------------- Layer 2: GATConv(512 -> 1 x 512) ----------------
    // h2 = r1 @ (sc*W2) + (sh@W2) (bf16 out) + fused logits (H=1: atomic into zeroed bufs)
    gemm_bf16<0, 1, 0, 1, 1, 0><<<GB, 256, 0, stream>>>(
        h_bf, W2t, bias2f, act_bf, nullptr, a2s, a2d, al_s2, al_d2, NN, DD, DD,
        nullptr, 0, nullptr, nullptr, nullptr, nullptr);
    alpha2_k<<<AB, 256, 0, stream>>>(al_s2, al_d2, csr_srcu, csr_dst, row_ptr, ea_al);
    gat_gather_k<1><<<GGB, 256, 0, stream>>>(act_bf, csr_srcu, ea_al, nullptr, row_ptr, perm, b2, h_bf);
    // r2 = relu(agg2 @ fc2 + b) (bf16 out) + fused BN stats
    gemm_bf16<1, 1, 1, 0, 8, 0><<<GB, 256, 0, stream>>>(
        h_bf, fc2t, fc2_b, act_bf, bnstatB, nullptr, nullptr, nullptr, nullptr, NN, DD, DD,
        nullptr, 0, nullptr, nullptr, nullptr, nullptr);

    // ---------------- head: final linear with BN2 fold fused per-block ----------------
    final_linear<<<NN / 4, 256, 0, stream>>>(act_bf, bnstatB, g2, be2, lin_w, lin_b, out);
}

// Round 10
// 329.213 us; speedup vs baseline: 1.0849x; 1.0849x over previous
//
#include <hip/hip_runtime.h>
#include <hip/hip_bf16.h>

// Problem constants (fixed by reference)
static constexpr int NN = 20000;   // nodes
static constexpr int EE = 320000;  // edges (without self loops)
static constexpr int ET = EE + NN; // edges incl self loops = 340000
static constexpr int DD = 512;     // hidden dim
static constexpr int FIN = 128;    // input features
static constexpr int ETP_MAX = ET + 7 * NN; // 480000: padded-CSR worst case

typedef __attribute__((ext_vector_type(8))) short short8;           // 8 bf16 (4 VGPRs)
typedef __attribute__((ext_vector_type(8))) unsigned short ushort8; // 8 src ids (4 VGPRs)
typedef __attribute__((ext_vector_type(4))) float f32x4;            // MFMA C/D frag

// float -> bf16 (round to nearest even), raw ushort bits
__device__ __forceinline__ unsigned short f2bf(float f) {
    unsigned u = __float_as_uint(f);
    u += 0x7fffu + ((u >> 16) & 1u);
    return (unsigned short)(u >> 16);
}
__device__ __forceinline__ float bf2f(unsigned short b) {
    return __uint_as_float(((unsigned)b) << 16);
}

// async global->LDS DMA, 16 B per lane. LDS dest = wave-uniform base + lane*16.
__device__ __forceinline__ void async_copy16(short* lds, const unsigned short* g) {
    __builtin_amdgcn_global_load_lds(
        (const __attribute__((address_space(1))) unsigned int*)g,
        (__attribute__((address_space(3))) unsigned int*)lds,
        16, 0, 0);
}

// ---------- scan + degree-bucketed node permutation (single block) ----------
// row_ptr: exclusive scan of PADDED row length ((deg+1+7)&~7); pad slots keep
// csr_srcu = 0xFFFF (memset 0xFF) -> alpha = 0 exactly downstream.
// perm: counting-sort by clamped degree DESCENDING (wave sees 8 similar-degree
// nodes). Chain-split atomics (R4 fix); parallel 512-bin scan (R5 fix).
__global__ void scan_k(const int* __restrict__ deg, int* __restrict__ row_ptr,
                       int* __restrict__ perm) {
    __shared__ int part[1024];
    __shared__ int hist16[16][512]; // per-wave hist -> cross-wave exclusive bases
    __shared__ int hbase[512];      // bin totals -> global exclusive base (scanned)
    __shared__ int btot[512];       // bin totals (scan input copy)
    int t = threadIdx.x;
    int wv = t >> 6;
    for (int k = t; k < 16 * 512; k += 1024) ((int*)hist16)[k] = 0;
    __syncthreads();
    const int CH = (NN + 1023) / 1024; // 20
    int start = t * CH;
    int end = min(start + CH, NN);
    int dl[CH]; // true length cache (one global pass)
    int s = 0;
    for (int i = start; i < end; ++i) {
        int d = deg[i] + 1;
        dl[i - start] = d;
        s += (d + 7) & ~7; // padded length
        atomicAdd(&hist16[wv][min(d, 511)], 1); // intra-wave chains only
    }
    part[t] = s;
    __syncthreads();
    // cross-wave per-bin exclusive prefix (atomic-free); totals in btot/hbase
    if (t < 512) {
        int base = 0;
#pragma unroll
        for (int w = 0; w < 16; ++w) { int c = hist16[w][t]; hist16[w][t] = base; base += c; }
        btot[t] = base;
        hbase[t] = base;
    }
    __syncthreads();
    // parallel inclusive scan of hbase[0..511] (Hillis-Steele)
    for (int off = 1; off < 512; off <<= 1) {
        int v = 0;
        if (t < 512 && t >= off) v = hbase[t - off];
        __syncthreads();
        if (t < 512) hbase[t] += v;
        __syncthreads();
    }
    if (t < 512) hbase[t] -= btot[t]; // exclusive
    // 1024-way prefix scan of per-thread padded sums
    for (int off = 1; off < 1024; off <<= 1) {
        int v = 0;
        if (t >= off) v = part[t - off];
        __syncthreads();
        part[t] += v;
        __syncthreads();
    }
    int base = (t == 0) ? 0 : part[t - 1];
    for (int i = start; i < end; ++i) { row_ptr[i] = base; base += (dl[i - start] + 7) & ~7; }
    if (t == 1023) row_ptr[NN] = part[1023]; // total padded slot count
    // scatter: pos = global bin base + cross-wave base + intra-wave rank
    for (int i = start; i < end; ++i) {
        int d = min(dl[i - start], 511);
        int r = atomicAdd(&hist16[wv][d], 1);
        int pos = hbase[d] + r;
        perm[NN - 1 - pos] = i; // descending degree order
    }
}

// ---------- merged prep: weight transpose + x->bf16 (float4) + count_deg ----------
static constexpr int TBLK = 208;                // transpose tile blocks (16 + 3*64)
static constexpr int SZ_X4 = NN * FIN / 4;      // 640,000 float4 units
static constexpr int XCB = (SZ_X4 + 255) / 256; // 2500 x-conversion blocks
static constexpr int CDB = (EE + 255) / 256;    // 1250 count-deg blocks
__global__ __launch_bounds__(256) void prep_all_k(
    const float* __restrict__ x, const float* __restrict__ W1,
    const float* __restrict__ fc1, const float* __restrict__ W2,
    const float* __restrict__ fc2,
    unsigned short* __restrict__ xb, unsigned short* __restrict__ W1t,
    unsigned short* __restrict__ fc1t, unsigned short* __restrict__ W2t,
    unsigned short* __restrict__ fc2t,
    const void* __restrict__ ei, int is64, int* __restrict__ deg) {
    int b = blockIdx.x;
    if (b < CDB) { // fused in-degree count (real edges)
        int i = b * 256 + threadIdx.x;
        if (i < EE) {
            int d = is64 ? (int)((const long long*)ei)[EE + i] : ((const int*)ei)[EE + i];
            atomicAdd(&deg[d], 1);
        }
        return;
    }
    b -= CDB;
    if (b < TBLK) { // 64x64 transpose tiles, coalesced reads AND writes
        __shared__ unsigned short tile[64][65];
        const float* src; unsigned short* dst; int rows, cols;
        if (b < 16)       { src = W1;  dst = W1t;  rows = FIN; cols = DD; }
        else if (b < 80)  { b -= 16;  src = fc1; dst = fc1t; rows = DD; cols = DD; }
        else if (b < 144) { b -= 80;  src = W2;  dst = W2t;  rows = DD; cols = DD; }
        else              { b -= 144; src = fc2; dst = fc2t; rows = DD; cols = DD; }
        int tc = cols / 64;
        int r0 = (b / tc) * 64, c0 = (b % tc) * 64;
        int t = threadIdx.x, lr = t >> 6, lc = t & 63;
#pragma unroll
        for (int p = 0; p < 16; ++p) {
            int r = lr + p * 4;
            tile[r][lc] = f2bf(src[(size_t)(r0 + r) * cols + c0 + lc]);
        }
        __syncthreads();
#pragma unroll
        for (int p = 0; p < 16; ++p) {
            int r = lr + p * 4; // output row = source col
            dst[(size_t)(c0 + r) * rows + r0 + lc] = tile[lc][r];
        }
        return;
    }
    int i = (b - TBLK) * 256 + threadIdx.x; // float4-granular x conversion
    if (i < SZ_X4) {
        float4 v = ((const float4*)x)[i];
        unsigned short o[4] = {f2bf(v.x), f2bf(v.y), f2bf(v.z), f2bf(v.w)};
        *(unsigned long long*)(xb + (size_t)i * 4) = *(const unsigned long long*)o;
    }
}

// ---------- bf16 MFMA GEMM: Cb[M,Nc] = bf16( A[M,K] @ Bt[Nc,K]^T (+bias)(+relu) ) ----------
// 128x128 tile, BK=64 (two 32-elem half-tiles), 256 threads = 4 waves (2x2),
// each wave 4x4 tiles of 16x16x32. Staging via async global_load_lds (16 B/lane).
// STATS: fused BN sum/sumsq. ALS: fused attention logits.
// FILLEX: blocks >= 640 run the (independent) fill_csr scatter instead.
template <int RELU, int HASBIAS, int STATS, int ALS, int H, int FILLEX>
__global__ __launch_bounds__(256) void gemm_bf16(const unsigned short* __restrict__ A,
                                                 const unsigned short* __restrict__ Bt,
                                                 const float* __restrict__ bias,
                                                 unsigned short* __restrict__ Cb,
                                                 float* __restrict__ bnstat,
                                                 const float* __restrict__ avs,
                                                 const float* __restrict__ avd,
                                                 float* __restrict__ al_s,
                                                 float* __restrict__ al_d,
                                                 int M, int Nc, int K,
                                                 const void* __restrict__ ei, int is64,
                                                 const int* __restrict__ rp,
                                                 int* __restrict__ cursor,
                                                 unsigned short* __restrict__ csr_srcu) {
    int id = blockIdx.x;
    if (FILLEX && id >= 640) { // fused fill_csr (independent of GEMM work)
        int e = (id - 640) * 256 + threadIdx.x;
        if (e >= ET) return;
        int s, d;
        if (e < EE) {
            if (is64) {
                const long long* p = (const long long*)ei;
                s = (int)p[e]; d = (int)p[EE + e];
            } else {
                const int* p = (const int*)ei;
                s = p[e]; d = p[EE + e];
            }
        } else {
            s = d = e - EE;
        }
        int pos = atomicAdd(&cursor[d], 1);
        csr_srcu[rp[d] + pos] = (unsigned short)s; // NN < 65536; pads stay 0xFFFF
        return;
    }
    int bm = ((id >> 5) << 3) + (id & 7); // 0..159
    int bn = (id >> 3) & 3;               // 0..3
    int m0 = bm * 128, n0 = bn * 128;
    if (m0 >= M) return; // padded m-tiles: whole block exits (no barrier executed)

    __shared__ short As0[128 * 32], As1[128 * 32]; // k-halves, 8 KB each
    __shared__ short Bs0[128 * 32], Bs1[128 * 32];
    int t = threadIdx.x;
    int lane = t & 63, w = t >> 6;
    int wm = w & 1, wn = w >> 1;           // wave quadrant (2x2 of 64x64)
    int quad = lane >> 4, mr = lane & 15;  // MFMA fragment indices
    int lrow = lane >> 2;                  // staging: row within 16-row group
    int lcol = (lane & 3) * 8;             // staging: elem offset within 32-elem half-row

    const unsigned short* Ag0 = A + (size_t)(m0 + w * 32 + lrow) * K + lcol;
    const unsigned short* Ag1 = A + (size_t)(m0 + w * 32 + 16 + lrow) * K + lcol;
    const unsigned short* Bg0 = Bt + (size_t)(n0 + w * 32 + lrow) * K + lcol;
    const unsigned short* Bg1 = Bt + (size_t)(n0 + w * 32 + 16 + lrow) * K + lcol;
    short* Al[2][2] = {{&As0[(w * 32) * 32], &As0[(w * 32 + 16) * 32]},
                       {&As1[(w * 32) * 32], &As1[(w * 32 + 16) * 32]}};
    short* Bl[2][2] = {{&Bs0[(w * 32) * 32], &Bs0[(w * 32 + 16) * 32]},
                       {&Bs1[(w * 32) * 32], &Bs1[(w * 32 + 16) * 32]}};

    f32x4 zero = {0.f, 0.f, 0.f, 0.f};
    f32x4 acc[4][4];
#pragma unroll
    for (int i = 0; i < 4; ++i)
#pragma unroll
        for (int j = 0; j < 4; ++j) acc[i][j] = zero;

    for (int k0 = 0; k0 < K; k0 += 64) {
        async_copy16(Al[0][0], Ag0 + k0);
        async_copy16(Al[1][0], Ag0 + k0 + 32);
        async_copy16(Al[0][1], Ag1 + k0);
        async_copy16(Al[1][1], Ag1 + k0 + 32);
        async_copy16(Bl[0][0], Bg0 + k0);
        async_copy16(Bl[1][0], Bg0 + k0 + 32);
        async_copy16(Bl[0][1], Bg1 + k0);
        async_copy16(Bl[1][1], Bg1 + k0 + 32);
        __syncthreads(); // drains vmcnt(0): DMA data landed in LDS
#pragma unroll
        for (int kp = 0; kp < 2; ++kp) {
            const short* Sa = kp ? As1 : As0;
            const short* Sb = kp ? Bs1 : Bs0;
            short8 af[4], bfr[4];
#pragma unroll
            for (int i = 0; i < 4; ++i) {
                af[i]  = *(const short8*)(&Sa[(wm * 64 + i * 16 + mr) * 32 + quad * 8]);
                bfr[i] = *(const short8*)(&Sb[(wn * 64 + i * 16 + mr) * 32 + quad * 8]);
            }
#pragma unroll
            for (int i = 0; i < 4; ++i)
#pragma unroll
                for (int j = 0; j < 4; ++j)
                    acc[i][j] = __builtin_amdgcn_mfma_f32_16x16x32_bf16(af[i], bfr[j], acc[i][j], 0, 0, 0);
        }
        __syncthreads(); // all waves done reading before next DMA overwrites
    }

    // epilogue: C/D layout col = lane&15, row = (lane>>4)*4 + reg  [m89/m91]
    float as_j[4], ad_j[4];
    if (ALS) {
#pragma unroll
        for (int j = 0; j < 4; ++j) {
            int n = n0 + wn * 64 + j * 16 + mr;
            as_j[j] = avs[n]; // a[H][C] flat == global col index for both H=8 and H=1
            ad_j[j] = avd[n];
        }
    }
    const int head = (H == 8) ? ((n0 + wn * 64) >> 6) : 0;
    float sj[4] = {0.f, 0.f, 0.f, 0.f}, qj[4] = {0.f, 0.f, 0.f, 0.f};
#pragma unroll
    for (int i = 0; i < 4; ++i) {
        int mb = m0 + wm * 64 + i * 16 + quad * 4;
#pragma unroll
        for (int r = 0; r < 4; ++r) {
            int m = mb + r;               // uniform across the 16 mr-lanes
            bool valid = (m < M);
            float ps = 0.f, pd = 0.f;
#pragma unroll
            for (int j = 0; j < 4; ++j) {
                int n = n0 + wn * 64 + j * 16 + mr;
                float v = acc[i][j][r];
                if (HASBIAS) v += bias[n];
                if (RELU) v = fmaxf(v, 0.f);
                unsigned short hb = f2bf(v);
                if (valid) Cb[(size_t)m * Nc + n] = hb;
                if (ALS) {
                    float vv = bf2f(hb); // match downstream bf16 read
                    ps += as_j[j] * vv;
                    pd += ad_j[j] * vv;
                }
                if (STATS && valid) { sj[j] += v; qj[j] += v * v; }
            }
            if (ALS) {
                ps += __shfl_xor(ps, 1); pd += __shfl_xor(pd, 1);
                ps += __shfl_xor(ps, 2); pd += __shfl_xor(pd, 2);
                ps += __shfl_xor(ps, 4); pd += __shfl_xor(pd, 4);
                ps += __shfl_xor(ps, 8); pd += __shfl_xor(pd, 8);
                if (mr == 0 && valid) {
                    if (H == 8) { al_s[m * 8 + head] = ps; al_d[m * 8 + head] = pd; }
                    else        { atomicAdd(&al_s[m], ps); atomicAdd(&al_d[m], pd); }
                }
            }
        }
    }
    if (STATS) {
#pragma unroll
        for (int j = 0; j < 4; ++j) {
            float s = sj[j], q = qj[j];
            s += __shfl_xor(s, 16); q += __shfl_xor(q, 16);
            s += __shfl_xor(s, 32); q += __shfl_xor(q, 32);
            if (lane < 16) { // quad==0 holds the 4-row-group total for this column
                int n = n0 + wn * 64 + j * 16 + mr;
                atomicAdd(&bnstat[n], s);
                atomicAdd(&bnstat[512 + n], q);
            }
        }
    }
}

// ---------- gather-aggregate v9: R8 structure, alpha fused for BOTH layers ----------
// 8 nodes x 8 lanes per wave; perm gives 8 similar-degree nodes/wave; rows padded
// to x8 (pad alpha = 0 exactly). slice = blockIdx&7 -> XCD pin (proven R2).
// R9 post-mortem: register-heavy h-load pipelining cratered occupancy (44->26%)
// and REGRESSED -- latency hiding must come from waves, not per-wave state.
// This is the proven R8 form (40 VGPR): immediate h-loads, edge-record prefetch.
// Alpha is computed in-loop for both H=8 (head==slice, each (edge,head) computed
// by exactly one slice) and H=1 (replicated per slice; exp is ~free in the
// latency-bound loop; kills the alpha2 dispatch + plane traffic + csr_dst).
// al_sv/al_dv: [NN][H] logit tables; hh = head index for this slice.
template <int H>
__global__ __launch_bounds__(256) void gat_gather_k(const unsigned short* __restrict__ hb,
                                                    const unsigned short* __restrict__ srcu,
                                                    const float* __restrict__ al_sv,
                                                    const float* __restrict__ al_dv,
                                                    const int* __restrict__ row_ptr,
                                                    const int* __restrict__ perm,
                                                    const float* __restrict__ bias,
                                                    unsigned short* __restrict__ outb) {
    int b = blockIdx.x;
    int s = b & 7;                  // col-slice 0..7 == XCD id == head (H=8)
    int g = b >> 3;                 // node group 0..624
    int t = threadIdx.x;
    int w = t >> 6, lane = t & 63;
    int grp = lane >> 3, cg = lane & 7;
    int n = perm[g * 32 + w * 8 + grp]; // NN = 625*32
    int col = s * 64 + cg * 8;      // this lane's 8 columns
    const char* hbase = (const char*)hb + col * 2; // + (src<<10) bytes
    int beg = row_ptr[n];
    int nb = (row_ptr[n + 1] - beg) >> 3; // exact batch count (padded rows), >= 1
    const int hh = (H == 8) ? s : 0;
    float ald = al_dv[n * H + hh];

    float acc[8] = {0.f, 0.f, 0.f, 0.f, 0.f, 0.f, 0.f, 0.f};
    float psum = 0.f;
    ushort8 sv = *(const ushort8*)(srcu + beg); // 16B aligned: beg % 8 == 0
    for (int bb = 1; bb <= nb; ++bb) {
        unsigned sa[8];
        float av[8];
#pragma unroll
        for (int u = 0; u < 8; ++u) {  // group-uniform: same-address broadcast loads
            unsigned sn = sv[u];
            bool pad = (sn == 0xFFFFu);
            sa[u] = pad ? 0u : sn;      // clamp: safe h-row, finite values
            float xx = al_sv[(size_t)sa[u] * H + hh] + ald;
            float a = __expf(fmaxf(xx, 0.2f * xx));
            av[u] = pad ? 0.f : a;
        }
        short8 hreg[8];
#pragma unroll
        for (int u = 0; u < 8; ++u)
            hreg[u] = *(const short8*)(hbase + ((size_t)sa[u] << 10));
        ushort8 svn;
        if (bb < nb) svn = *(const ushort8*)(srcu + beg + bb * 8); // prefetch
#pragma unroll
        for (int u = 0; u < 8; ++u) psum += av[u];
#pragma unroll
        for (int u = 0; u < 8; ++u)
#pragma unroll
            for (int j = 0; j < 8; ++j)
                acc[j] = fmaf(av[u], bf2f((unsigned short)hreg[u][j]), acc[j]);
        if (bb < nb) sv = svn;
    }
    float inv = 1.0f / psum;
    float4 b0 = *(const float4*)(bias + col);
    float4 b1 = *(const float4*)(bias + col + 4);
    float bz[8] = {b0.x, b0.y, b0.z, b0.w, b1.x, b1.y, b1.z, b1.w};
    unsigned short ov[8];
#pragma unroll
    for (int j = 0; j < 8; ++j) ov[j] = f2bf(acc[j] * inv + bz[j]);
    *(int4*)(outb + (size_t)n * DD + col) = *(const int4*)ov;
}

// ---------- fold BN1 into W2: W2t[n][k] *= sc[k] (in place); bias2[n] = sum_k sh[k]*W2t[n][k] ----------
__global__ __launch_bounds__(256) void fold1_k(const float* __restrict__ stat,
                                               const float* __restrict__ g,
                                               const float* __restrict__ be,
                                               unsigned short* __restrict__ W2t,
                                               float* __restrict__ bias2) {
    int t = threadIdx.x;
    int n = blockIdx.x * 4 + (t >> 6); // 128 blocks -> n in [0,512)
    int lane = t & 63;
    float pb = 0.f;
#pragma unroll
    for (int j = 0; j < 8; ++j) {
        int k = lane * 8 + j;
        float mean = stat[k] * (1.0f / NN);
        float var = stat[512 + k] * (1.0f / NN) - mean * mean;
        float sc = g[k] * rsqrtf(var + 1e-5f);
        float sh = be[k] - mean * sc;
        float wv = bf2f(W2t[n * DD + k]);
        W2t[n * DD + k] = f2bf(sc * wv);
        pb += sh * wv;
    }
    for (int off = 32; off; off >>= 1) pb += __shfl_down(pb, off);
    if (lane == 0) bias2[n] = pb;
}

// ---------- final linear with BN2 fold fused per-block ----------
// Each block (4 waves = 4 nodes) first cooperatively folds BN2 into LDS
// (w01[c] = sc_c * lin_w[c][.]; k0/k1 = sum of const terms), then each wave
// does the 512-dot for its node. stat/g/be/lw are 8 KB total -> L2-hot.
__global__ __launch_bounds__(256) void final_linear(const unsigned short* __restrict__ xb,
                                                    const float* __restrict__ stat,
                                                    const float* __restrict__ g,
                                                    const float* __restrict__ be,
                                                    const float* __restrict__ lw,
                                                    const float* __restrict__ lb,
                                                    float* __restrict__ out) {
    __shared__ float w01[1024];
    __shared__ float red[512];
    int t = threadIdx.x;
    float rr0 = 0.f, rr1 = 0.f;
#pragma unroll
    for (int q = 0; q < 2; ++q) {
        int c = t * 2 + q; // 0..511
        float mean = stat[c] * (1.0f / NN);
        float var = stat[512 + c] * (1.0f / NN) - mean * mean;
        float sc = g[c] * rsqrtf(var + 1e-5f);
        float sh = be[c] - mean * sc;
        float w0 = lw[2 * c], w1 = lw[2 * c + 1];
        w01[2 * c] = sc * w0;
        w01[2 * c + 1] = sc * w1;
        rr0 = fmaf(sh, w0, rr0);
        rr1 = fmaf(sh, w1, rr1);
    }
    red[t] = rr0;
    red[256 + t] = rr1;
    __syncthreads();
    for (int off = 128; off; off >>= 1) {
        if (t < off) { red[t] += red[t + off]; red[256 + t] += red[256 + t + off]; }
        __syncthreads();
    }
    float k0 = red[0] + lb[0], k1 = red[256] + lb[1];

    int wave = blockIdx.x * 4 + (t >> 6);
    int lane = t & 63;
    short8 hv = *(const short8*)(xb + (size_t)wave * DD + lane * 8);
    float p0 = 0.f, p1 = 0.f;
#pragma unroll
    for (int j = 0; j < 8; ++j) {
        int c = lane * 8 + j;
        float h = bf2f((unsigned short)hv[j]);
        p0 = fmaf(h, w01[2 * c], p0);
        p1 = fmaf(h, w01[2 * c + 1], p1);
    }
    for (int off = 32; off; off >>= 1) {
        p0 += __shfl_down(p0, off);
        p1 += __shfl_down(p1, off);
    }
    if (lane == 0) {
        out[wave * 2 + 0] = fmaxf(p0 + k0, 0.f);
        out[wave * 2 + 1] = fmaxf(p1 + k1, 0.f);
    }
}

extern "C" void kernel_launch(void* const* d_in, const int* in_sizes, int n_in,
                              void* d_out, int out_size, void* d_ws, size_t ws_size,
                              hipStream_t stream) {
    const float* x     = (const float*)d_in[0];
    const void*  ei    = d_in[1];
    const float* W1    = (const float*)d_in[2];
    const float* a1s   = (const float*)d_in[3];
    const float* a1d   = (const float*)d_in[4];
    const float* b1    = (const float*)d_in[5];
    const float* W2    = (const float*)d_in[6];
    const float* a2s   = (const float*)d_in[7];
    const float* a2d   = (const float*)d_in[8];
    const float* b2    = (const float*)d_in[9];
    const float* fc1_w = (const float*)d_in[10];
    const float* fc1_b = (const float*)d_in[11];
    const float* g1    = (const float*)d_in[12];
    const float* be1   = (const float*)d_in[13];
    const float* fc2_w = (const float*)d_in[14];
    const float* fc2_b = (const float*)d_in[15];
    const float* g2    = (const float*)d_in[16];
    const float* be2   = (const float*)d_in[17];
    const float* lin_w = (const float*)d_in[18];
    const float* lin_b = (const float*)d_in[19];
    float* out = (float*)d_out;

    // workspace carve-up (256B aligned)
    char* ws = (char*)d_ws;
    auto alloc = [&](size_t bytes) {
        void* p = (void*)ws;
        ws += (bytes + 255) & ~size_t(255);
        return p;
    };
    unsigned short* h_bf    = (unsigned short*)alloc((size_t)NN * DD * 2); // ping
    unsigned short* act_bf  = (unsigned short*)alloc((size_t)NN * DD * 2); // pong
    unsigned short* W1t     = (unsigned short*)alloc((size_t)DD * FIN * 2);
    unsigned short* fc1t    = (unsigned short*)alloc((size_t)DD * DD * 2);
    unsigned short* W2t     = (unsigned short*)alloc((size_t)DD * DD * 2);
    unsigned short* fc2t    = (unsigned short*)alloc((size_t)DD * DD * 2);
    float*          al_s    = (float*)alloc((size_t)NN * 8 * 4);           // layer-1 logits (H=8)
    float*          al_d    = (float*)alloc((size_t)NN * 8 * 4);
    int*            row_ptr = (int*)alloc((size_t)(NN + 1) * 4);
    int*            perm    = (int*)alloc((size_t)NN * 4);                 // degree-sorted nodes
    float*          bias2f  = (float*)alloc(512 * 4);                      // BN1-fold bias for W2 GEMM
    // zero-region: deg + cursor + bnstatA/B + al_s2 + al_d2 (ONE memset)
    int*            deg     = (int*)alloc((size_t)(4 * NN + 2048) * 4);
    int*            cursor  = deg + NN;
    float*          bnstatA = (float*)(deg + 2 * NN);
    float*          bnstatB = bnstatA + 1024;
    float*          al_s2   = bnstatA + 2048;
    float*          al_d2   = al_s2 + NN;
    // 0xFF-region: csr_srcu (pad slots stay 0xFFFF -> alpha 0 downstream)
    unsigned short* csr_srcu = (unsigned short*)alloc((size_t)ETP_MAX * 2);

    // --- host-side edge dtype detection: in_sizes[1] is byte size of edge_index ---
    const int is64 = (in_sizes[1] >= (int)(2u * EE * 8u)) ? 1 : 0;

    // --- init via graph-capturable async memsets (2 total) ---
    hipMemsetAsync(deg, 0, (size_t)(4 * NN + 2048) * 4, stream);
    hipMemsetAsync(csr_srcu, 0xFF, (size_t)ETP_MAX * 2, stream);

    // --- merged: count_deg + weight transpose + x conversion (one launch) ---
    unsigned short* x_bf = act_bf; // consumed by GEMM1 before gat_gather_k overwrites
    const int prep_blocks = CDB + TBLK + XCB;
    prep_all_k<<<prep_blocks, 256, 0, stream>>>(x, W1, fc1_w, W2, fc2_w,
                                                x_bf, W1t, fc1t, W2t, fc2t,
                                                ei, is64, deg);
    // padded row_ptr + degree-bucketed perm (single block, chain-split atomics)
    scan_k<<<1, 1024, 0, stream>>>(deg, row_ptr, perm);

    const int GB = 640;              // GEMM blocks: 160 padded m-tiles x 4 n-tiles
    const int FB = (ET + 255) / 256; // fused fill_csr blocks (real slots only)
    const int GGB = 8 * (NN / 32);   // gather: 8 col-slices x 625 node-groups = 5000

    // ---------------- Layer 1: GATConv(128 -> 8 x 64) ----------------
    // h1 = x @ W1 (bf16 out) + fused logits + fused fill_csr (independent blocks)
    gemm_bf16<0, 0, 0, 1, 8, 1><<<GB + FB, 256, 0, stream>>>(
        x_bf, W1t, nullptr, h_bf, nullptr, a1s, a1d, al_s, al_d, NN, DD, FIN,
        ei, is64, row_ptr, cursor, csr_srcu);
    // gather with fused alpha (head == slice; no alpha kernel)
    gat_gather_k<8><<<GGB, 256, 0, stream>>>(h_bf, csr_srcu, al_s, al_d, row_ptr, perm, b1, act_bf);
    // r1 = relu(agg1 @ fc1 + b) (bf16 out) + fused BN stats
    gemm_bf16<1, 1, 1, 0, 8, 0><<<GB, 256, 0, stream>>>(
        act_bf, fc1t, fc1_b, h_bf, bnstatA, nullptr, nullptr, nullptr, nullptr, NN, DD, DD,
        nullptr, 0, nullptr, nullptr, nullptr);
    // fold BN1 into W2 weights + bias
    fold1_k<<<128, 256, 0, stream>>>(bnstatA, g1, be1, W2t, bias2f);

    // ---------------- Layer 2: GATConv(512 -> 1 x 512) ----------------
    // h2 = r1 @ (sc*W2) + (sh@W2) (bf16 out) + fused logits (H=1: atomic into zeroed bufs)
    gemm_bf16<0, 1, 0, 1, 1, 0><<<GB, 256, 0, stream>>>(
        h_bf, W2t, bias2f, act_bf, nullptr, a2s, a2d, al_s2, al_d2, NN, DD, DD,
        nullptr, 0, nullptr, nullptr, nullptr);
    // gather with fused alpha (H=1: exp replicated per slice -- absorbed by idle slots)
    gat_gather_k<1><<<GGB, 256, 0, stream>>>(act_bf, csr_srcu, al_s2, al_d2, row_ptr, perm, b2, h_bf);
    // r2 = relu(agg2 @ fc2 + b) (bf16 out) + fused BN stats
    gemm_bf16<1, 1, 1, 0, 8, 0><<<GB, 256, 0, stream>>>(
        h_bf, fc2t, fc2_b, act_bf, bnstatB, nullptr, nullptr, nullptr, nullptr, NN, DD, DD,
        nullptr, 0, nullptr, nullptr, nullptr);

    // ---------------- head: final linear with BN2 fold fused per-block ----------------
    final_linear<<<NN / 4, 256, 0, stream>>>(act_bf, bnstatB, g2, be2, lin_w, lin_b, out);
}

// Round 12
// 326.278 us; speedup vs baseline: 1.0947x; 1.0090x over previous
//
#include <hip/hip_runtime.h>
#include <hip/hip_bf16.h>

// Problem constants (fixed by reference)
static constexpr int NN = 20000;   // nodes
static constexpr int EE = 320000;  // edges (without self loops)
static constexpr int ET = EE + NN; // edges incl self loops = 340000
static constexpr int DD = 512;     // hidden dim
static constexpr int FIN = 128;    // input features
static constexpr int ETP_MAX = ET + 7 * NN; // 480000: padded-CSR worst case

typedef __attribute__((ext_vector_type(8))) short short8;           // 8 bf16 (4 VGPRs)
typedef __attribute__((ext_vector_type(8))) unsigned short ushort8; // 8 src ids (4 VGPRs)
typedef __attribute__((ext_vector_type(4))) float f32x4;            // MFMA C/D frag

// float -> bf16 (round to nearest even), raw ushort bits
__device__ __forceinline__ unsigned short f2bf(float f) {
    unsigned u = __float_as_uint(f);
    u += 0x7fffu + ((u >> 16) & 1u);
    return (unsigned short)(u >> 16);
}
__device__ __forceinline__ float bf2f(unsigned short b) {
    return __uint_as_float(((unsigned)b) << 16);
}

// async global->LDS DMA, 16 B per lane. LDS dest = wave-uniform base + lane*16.
__device__ __forceinline__ void async_copy16(short* lds, const unsigned short* g) {
    __builtin_amdgcn_global_load_lds(
        (const __attribute__((address_space(1))) unsigned int*)g,
        (__attribute__((address_space(3))) unsigned int*)lds,
        16, 0, 0);
}

// ---------- scan + degree-bucketed node permutation (single block) ----------
// row_ptr: exclusive scan of PADDED row length ((deg+1+7)&~7); pad slots keep
// csr_srcu = 0xFFFF (memset 0xFF) -> alpha = 0 exactly downstream.
// perm: counting-sort by clamped degree DESCENDING (wave sees 8 similar-degree
// nodes). Chain-split atomics (R4 fix). R11: both prefix scans are 3-phase
// wave scans (__shfl_up intra-wave + single-wave cross-wave) -- ~6 barriers
// total vs ~40 for the old Hillis-Steele pair.
__global__ void scan_k(const int* __restrict__ deg, int* __restrict__ row_ptr,
                       int* __restrict__ perm) {
    __shared__ int hist16[16][512]; // per-wave hist -> cross-wave exclusive bases
    __shared__ int hbase[512];      // bin totals -> global exclusive base (scanned)
    __shared__ int wsum[16];        // per-wave padded-sum totals
    __shared__ int bsum[8];         // per-wave bin-scan totals
    int t = threadIdx.x;
    int lane = t & 63, wv = t >> 6;
    for (int k = t; k < 16 * 512; k += 1024) ((int*)hist16)[k] = 0;
    __syncthreads();
    const int CH = (NN + 1023) / 1024; // 20
    int start = t * CH;
    int end = min(start + CH, NN);
    int dl[CH]; // true length cache (one global pass)
    int s = 0;
    for (int i = start; i < end; ++i) {
        int d = deg[i] + 1;
        dl[i - start] = d;
        s += (d + 7) & ~7; // padded length
        atomicAdd(&hist16[wv][min(d, 511)], 1); // intra-wave chains only
    }
    // wave-level inclusive scan of per-thread padded sums (no barriers)
    int incl = s;
#pragma unroll
    for (int off = 1; off < 64; off <<= 1) {
        int v = __shfl_up(incl, off);
        if (lane >= off) incl += v;
    }
    if (lane == 63) wsum[wv] = incl;
    __syncthreads(); // hist16 atomics + wsum complete
    // cross-wave per-bin exclusive prefix (atomic-free); hbase[b] = bin total
    if (t < 512) {
        int base = 0;
#pragma unroll
        for (int w = 0; w < 16; ++w) { int c = hist16[w][t]; hist16[w][t] = base; base += c; }
        hbase[t] = base;
    }
    // cross-wave exclusive bases for the padded-sum scan (wave 0, lanes 0..15)
    if (wv == 0 && lane < 16) {
        int v = wsum[lane];
        int inc = v;
#pragma unroll
        for (int off = 1; off < 16; off <<= 1) {
            int u = __shfl_up(inc, off, 16);
            if (lane >= off) inc += u;
        }
        wsum[lane] = inc - v; // exclusive
    }
    __syncthreads();
    // row_ptr fill from exclusive prefix
    int base = wsum[wv] + incl - s;
    for (int i = start; i < end; ++i) { row_ptr[i] = base; base += (dl[i - start] + 7) & ~7; }
    if (t == 1023) row_ptr[NN] = base; // total padded slot count
    // 512-bin exclusive scan of hbase via wave scans (8 waves x 64 bins)
    int btot_own = 0, bincl = 0;
    if (wv < 8) {
        btot_own = hbase[wv * 64 + lane];
        bincl = btot_own;
#pragma unroll
        for (int off = 1; off < 64; off <<= 1) {
            int v = __shfl_up(bincl, off);
            if (lane >= off) bincl += v;
        }
        if (lane == 63) bsum[wv] = bincl;
    }
    __syncthreads();
    if (wv == 0 && lane < 8) {
        int v = bsum[lane];
        int inc = v;
#pragma unroll
        for (int off = 1; off < 8; off <<= 1) {
            int u = __shfl_up(inc, off, 8);
            if (lane >= off) inc += u;
        }
        bsum[lane] = inc - v; // exclusive
    }
    __syncthreads();
    if (wv < 8) hbase[wv * 64 + lane] = bsum[wv] + bincl - btot_own; // exclusive bin base
    __syncthreads();
    // scatter: pos = global bin base + cross-wave base + intra-wave rank
    for (int i = start; i < end; ++i) {
        int d = min(dl[i - start], 511);
        int r = atomicAdd(&hist16[wv][d], 1);
        int pos = hbase[d] + r;
        perm[NN - 1 - pos] = i; // descending degree order
    }
}

// ---------- merged prep: weight transpose + x->bf16 (float4) + count_deg ----------
static constexpr int TBLK = 208;                // transpose tile blocks (16 + 3*64)
static constexpr int SZ_X4 = NN * FIN / 4;      // 640,000 float4 units
static constexpr int XCB = (SZ_X4 + 255) / 256; // 2500 x-conversion blocks
static constexpr int CDB = (EE + 255) / 256;    // 1250 count-deg blocks
__global__ __launch_bounds__(256) void prep_all_k(
    const float* __restrict__ x, const float* __restrict__ W1,
    const float* __restrict__ fc1, const float* __restrict__ W2,
    const float* __restrict__ fc2,
    unsigned short* __restrict__ xb, unsigned short* __restrict__ W1t,
    unsigned short* __restrict__ fc1t, unsigned short* __restrict__ W2t,
    unsigned short* __restrict__ fc2t,
    const void* __restrict__ ei, int is64, int* __restrict__ deg) {
    int b = blockIdx.x;
    if (b < CDB) { // fused in-degree count (real edges)
        int i = b * 256 + threadIdx.x;
        if (i < EE) {
            int d = is64 ? (int)((const long long*)ei)[EE + i] : ((const int*)ei)[EE + i];
            atomicAdd(&deg[d], 1);
        }
        return;
    }
    b -= CDB;
    if (b < TBLK) { // 64x64 transpose tiles, coalesced reads AND writes
        __shared__ unsigned short tile[64][65];
        const float* src; unsigned short* dst; int rows, cols;
        if (b < 16)       { src = W1;  dst = W1t;  rows = FIN; cols = DD; }
        else if (b < 80)  { b -= 16;  src = fc1; dst = fc1t; rows = DD; cols = DD; }
        else if (b < 144) { b -= 80;  src = W2;  dst = W2t;  rows = DD; cols = DD; }
        else              { b -= 144; src = fc2; dst = fc2t; rows = DD; cols = DD; }
        int tc = cols / 64;
        int r0 = (b / tc) * 64, c0 = (b % tc) * 64;
        int t = threadIdx.x, lr = t >> 6, lc = t & 63;
#pragma unroll
        for (int p = 0; p < 16; ++p) {
            int r = lr + p * 4;
            tile[r][lc] = f2bf(src[(size_t)(r0 + r) * cols + c0 + lc]);
        }
        __syncthreads();
#pragma unroll
        for (int p = 0; p < 16; ++p) {
            int r = lr + p * 4; // output row = source col
            dst[(size_t)(c0 + r) * rows + r0 + lc] = tile[lc][r];
        }
        return;
    }
    int i = (b - TBLK) * 256 + threadIdx.x; // float4-granular x conversion
    if (i < SZ_X4) {
        float4 v = ((const float4*)x)[i];
        unsigned short o[4] = {f2bf(v.x), f2bf(v.y), f2bf(v.z), f2bf(v.w)};
        *(unsigned long long*)(xb + (size_t)i * 4) = *(const unsigned long long*)o;
    }
}

// ---------- bf16 MFMA GEMM: Cb[M,Nc] = bf16( A[M,K] @ Bt[Nc,K]^T (+bias)(+relu) ) ----------
// 128x128 tile, BK=64 (two 32-elem half-tiles), 256 threads = 4 waves (2x2),
// each wave 4x4 tiles of 16x16x32. Staging via async global_load_lds (16 B/lane).
// STATS: fused BN sum/sumsq. ALS: fused attention logits (HEAD-MAJOR al[head][node]
// for H=8 -> per-XCD 80 KB plane, L2-resident in the gather).
// FILLEX: blocks >= 640 run the (independent) fill_csr scatter instead.
template <int RELU, int HASBIAS, int STATS, int ALS, int H, int FILLEX>
__global__ __launch_bounds__(256) void gemm_bf16(const unsigned short* __restrict__ A,
                                                 const unsigned short* __restrict__ Bt,
                                                 const float* __restrict__ bias,
                                                 unsigned short* __restrict__ Cb,
                                                 float* __restrict__ bnstat,
                                                 const float* __restrict__ avs,
                                                 const float* __restrict__ avd,
                                                 float* __restrict__ al_s,
                                                 float* __restrict__ al_d,
                                                 int M, int Nc, int K,
                                                 const void* __restrict__ ei, int is64,
                                                 const int* __restrict__ rp,
                                                 int* __restrict__ cursor,
                                                 unsigned short* __restrict__ csr_srcu) {
    int id = blockIdx.x;
    if (FILLEX && id >= 640) { // fused fill_csr (independent of GEMM work)
        int e = (id - 640) * 256 + threadIdx.x;
        if (e >= ET) return;
        int s, d;
        if (e < EE) {
            if (is64) {
                const long long* p = (const long long*)ei;
                s = (int)p[e]; d = (int)p[EE + e];
            } else {
                const int* p = (const int*)ei;
                s = p[e]; d = p[EE + e];
            }
        } else {
            s = d = e - EE;
        }
        int pos = atomicAdd(&cursor[d], 1);
        csr_srcu[rp[d] + pos] = (unsigned short)s; // NN < 65536; pads stay 0xFFFF
        return;
    }
    int bm = ((id >> 5) << 3) + (id & 7); // 0..159
    int bn = (id >> 3) & 3;               // 0..3
    int m0 = bm * 128, n0 = bn * 128;
    if (m0 >= M) return; // padded m-tiles: whole block exits (no barrier executed)

    __shared__ short As0[128 * 32], As1[128 * 32]; // k-halves, 8 KB each
    __shared__ short Bs0[128 * 32], Bs1[128 * 32];
    int t = threadIdx.x;
    int lane = t & 63, w = t >> 6;
    int wm = w & 1, wn = w >> 1;           // wave quadrant (2x2 of 64x64)
    int quad = lane >> 4, mr = lane & 15;  // MFMA fragment indices
    int lrow = lane >> 2;                  // staging: row within 16-row group
    int lcol = (lane & 3) * 8;             // staging: elem offset within 32-elem half-row

    const unsigned short* Ag0 = A + (size_t)(m0 + w * 32 + lrow) * K + lcol;
    const unsigned short* Ag1 = A + (size_t)(m0 + w * 32 + 16 + lrow) * K + lcol;
    const unsigned short* Bg0 = Bt + (size_t)(n0 + w * 32 + lrow) * K + lcol;
    const unsigned short* Bg1 = Bt + (size_t)(n0 + w * 32 + 16 + lrow) * K + lcol;
    short* Al[2][2] = {{&As0[(w * 32) * 32], &As0[(w * 32 + 16) * 32]},
                       {&As1[(w * 32) * 32], &As1[(w * 32 + 16) * 32]}};
    short* Bl[2][2] = {{&Bs0[(w * 32) * 32], &Bs0[(w * 32 + 16) * 32]},
                       {&Bs1[(w * 32) * 32], &Bs1[(w * 32 + 16) * 32]}};

    f32x4 zero = {0.f, 0.f, 0.f, 0.f};
    f32x4 acc[4][4];
#pragma unroll
    for (int i = 0; i < 4; ++i)
#pragma unroll
        for (int j = 0; j < 4; ++j) acc[i][j] = zero;

    for (int k0 = 0; k0 < K; k0 += 64) {
        async_copy16(Al[0][0], Ag0 + k0);
        async_copy16(Al[1][0], Ag0 + k0 + 32);
        async_copy16(Al[0][1], Ag1 + k0);
        async_copy16(Al[1][1], Ag1 + k0 + 32);
        async_copy16(Bl[0][0], Bg0 + k0);
        async_copy16(Bl[1][0], Bg0 + k0 + 32);
        async_copy16(Bl[0][1], Bg1 + k0);
        async_copy16(Bl[1][1], Bg1 + k0 + 32);
        __syncthreads(); // drains vmcnt(0): DMA data landed in LDS
#pragma unroll
        for (int kp = 0; kp < 2; ++kp) {
            const short* Sa = kp ? As1 : As0;
            const short* Sb = kp ? Bs1 : Bs0;
            short8 af[4], bfr[4];
#pragma unroll
            for (int i = 0; i < 4; ++i) {
                af[i]  = *(const short8*)(&Sa[(wm * 64 + i * 16 + mr) * 32 + quad * 8]);
                bfr[i] = *(const short8*)(&Sb[(wn * 64 + i * 16 + mr) * 32 + quad * 8]);
            }
#pragma unroll
            for (int i = 0; i < 4; ++i)
#pragma unroll
                for (int j = 0; j < 4; ++j)
                    acc[i][j] = __builtin_amdgcn_mfma_f32_16x16x32_bf16(af[i], bfr[j], acc[i][j], 0, 0, 0);
        }
        __syncthreads(); // all waves done reading before next DMA overwrites
    }

    // epilogue: C/D layout col = lane&15, row = (lane>>4)*4 + reg  [m89/m91]
    float as_j[4], ad_j[4];
    if (ALS) {
#pragma unroll
        for (int j = 0; j < 4; ++j) {
            int n = n0 + wn * 64 + j * 16 + mr;
            as_j[j] = avs[n]; // a[H][C] flat == global col index for both H=8 and H=1
            ad_j[j] = avd[n];
        }
    }
    const int head = (H == 8) ? ((n0 + wn * 64) >> 6) : 0;
    float sj[4] = {0.f, 0.f, 0.f, 0.f}, qj[4] = {0.f, 0.f, 0.f, 0.f};
#pragma unroll
    for (int i = 0; i < 4; ++i) {
        int mb = m0 + wm * 64 + i * 16 + quad * 4;
#pragma unroll
        for (int r = 0; r < 4; ++r) {
            int m = mb + r;               // uniform across the 16 mr-lanes
            bool valid = (m < M);
            float ps = 0.f, pd = 0.f;
#pragma unroll
            for (int j = 0; j < 4; ++j) {
                int n = n0 + wn * 64 + j * 16 + mr;
                float v = acc[i][j][r];
                if (HASBIAS) v += bias[n];
                if (RELU) v = fmaxf(v, 0.f);
                unsigned short hb = f2bf(v);
                if (valid) Cb[(size_t)m * Nc + n] = hb;
                if (ALS) {
                    float vv = bf2f(hb); // match downstream bf16 read
                    ps += as_j[j] * vv;
                    pd += ad_j[j] * vv;
                }
                if (STATS && valid) { sj[j] += v; qj[j] += v * v; }
            }
            if (ALS) {
                ps += __shfl_xor(ps, 1); pd += __shfl_xor(pd, 1);
                ps += __shfl_xor(ps, 2); pd += __shfl_xor(pd, 2);
                ps += __shfl_xor(ps, 4); pd += __shfl_xor(pd, 4);
                ps += __shfl_xor(ps, 8); pd += __shfl_xor(pd, 8);
                if (mr == 0 && valid) {
                    if (H == 8) { // HEAD-MAJOR: al[head][node]
                        al_s[(size_t)head * NN + m] = ps;
                        al_d[(size_t)head * NN + m] = pd;
                    } else {
                        atomicAdd(&al_s[m], ps); atomicAdd(&al_d[m], pd);
                    }
                }
            }
        }
    }
    if (STATS) {
#pragma unroll
        for (int j = 0; j < 4; ++j) {
            float s = sj[j], q = qj[j];
            s += __shfl_xor(s, 16); q += __shfl_xor(q, 16);
            s += __shfl_xor(s, 32); q += __shfl_xor(q, 32);
            if (lane < 16) { // quad==0 holds the 4-row-group total for this column
                int n = n0 + wn * 64 + j * 16 + mr;
                atomicAdd(&bnstat[n], s);
                atomicAdd(&bnstat[512 + n], q);
            }
        }
    }
}

// ---------- gather-aggregate v10: R8 structure + head-major alpha planes ----------
// 8 nodes x 8 lanes per wave; perm gives 8 similar-degree nodes/wave; rows padded
// to x8 (pad alpha = 0 exactly). slice = blockIdx&7 -> XCD pin (proven R2).
// Alpha fused in-loop for both layers (R10). R11: logit tables are HEAD-MAJOR
// al[head][node] -> slice s reads only its own 80 KB plane (L2-resident) instead
// of scattering 4B reads across the whole 640 KB [node][head] table; also one
// fewer VALU op per edge (index = sa, not sa*8+hh).
template <int H>
__global__ __launch_bounds__(256) void gat_gather_k(const unsigned short* __restrict__ hb,
                                                    const unsigned short* __restrict__ srcu,
                                                    const float* __restrict__ al_sv, // [H][NN]
                                                    const float* __restrict__ al_dv, // [H][NN]
                                                    const int* __restrict__ row_ptr,
                                                    const int* __restrict__ perm,
                                                    const float* __restrict__ bias,
                                                    unsigned short* __restrict__ outb) {
    int b = blockIdx.x;
    int s = b & 7;                  // col-slice 0..7 == XCD id == head (H=8)
    int g = b >> 3;                 // node group 0..624
    int t = threadIdx.x;
    int w = t >> 6, lane = t & 63;
    int grp = lane >> 3, cg = lane & 7;
    int n = perm[g * 32 + w * 8 + grp]; // NN = 625*32
    int col = s * 64 + cg * 8;      // this lane's 8 columns
    const char* hbase = (const char*)hb + col * 2; // + (src<<10) bytes
    int beg = row_ptr[n];
    int nb = (row_ptr[n + 1] - beg) >> 3; // exact batch count (padded rows), >= 1
    const size_t hoff = (H == 8) ? (size_t)s * NN : 0;
    const float* asp = al_sv + hoff; // this slice's 80 KB logit plane
    float ald = al_dv[hoff + n];

    float acc[8] = {0.f, 0.f, 0.f, 0.f, 0.f, 0.f, 0.f, 0.f};
    float psum = 0.f;
    ushort8 sv = *(const ushort8*)(srcu + beg); // 16B aligned: beg % 8 == 0
    for (int bb = 1; bb <= nb; ++bb) {
        unsigned sa[8];
        float av[8];
#pragma unroll
        for (int u = 0; u < 8; ++u) {  // group-uniform: same-address broadcast loads
            unsigned sn = sv[u];
            bool pad = (sn == 0xFFFFu);
            sa[u] = pad ? 0u : sn;      // clamp: safe h-row, finite values
            float xx = asp[sa[u]] + ald;
            float a = __expf(fmaxf(xx, 0.2f * xx));
            av[u] = pad ? 0.f : a;
        }
        short8 hreg[8];
#pragma unroll
        for (int u = 0; u < 8; ++u)
            hreg[u] = *(const short8*)(hbase + ((size_t)sa[u] << 10));
        ushort8 svn;
        if (bb < nb) svn = *(const ushort8*)(srcu + beg + bb * 8); // prefetch
#pragma unroll
        for (int u = 0; u < 8; ++u) psum += av[u];
#pragma unroll
        for (int u = 0; u < 8; ++u)
#pragma unroll
            for (int j = 0; j < 8; ++j)
                acc[j] = fmaf(av[u], bf2f((unsigned short)hreg[u][j]), acc[j]);
        if (bb < nb) sv = svn;
    }
    float inv = 1.0f / psum;
    float4 b0 = *(const float4*)(bias + col);
    float4 b1 = *(const float4*)(bias + col + 4);
    float bz[8] = {b0.x, b0.y, b0.z, b0.w, b1.x, b1.y, b1.z, b1.w};
    unsigned short ov[8];
#pragma unroll
    for (int j = 0; j < 8; ++j) ov[j] = f2bf(acc[j] * inv + bz[j]);
    *(int4*)(outb + (size_t)n * DD + col) = *(const int4*)ov;
}

// ---------- fold BN1 into W2: W2t[n][k] *= sc[k] (in place); bias2[n] = sum_k sh[k]*W2t[n][k] ----------
__global__ __launch_bounds__(256) void fold1_k(const float* __restrict__ stat,
                                               const float* __restrict__ g,
                                               const float* __restrict__ be,
                                               unsigned short* __restrict__ W2t,
                                               float* __restrict__ bias2) {
    int t = threadIdx.x;
    int n = blockIdx.x * 4 + (t >> 6); // 128 blocks -> n in [0,512)
    int lane = t & 63;
    float pb = 0.f;
#pragma unroll
    for (int j = 0; j < 8; ++j) {
        int k = lane * 8 + j;
        float mean = stat[k] * (1.0f / NN);
        float var = stat[512 + k] * (1.0f / NN) - mean * mean;
        float sc = g[k] * rsqrtf(var + 1e-5f);
        float sh = be[k] - mean * sc;
        float wv = bf2f(W2t[n * DD + k]);
        W2t[n * DD + k] = f2bf(sc * wv);
        pb += sh * wv;
    }
    for (int off = 32; off; off >>= 1) pb += __shfl_down(pb, off);
    if (lane == 0) bias2[n] = pb;
}

// ---------- final linear with BN2 fold fused per-block ----------
// Each block (4 waves = 4 nodes) first cooperatively folds BN2 into LDS
// (w01[c] = sc_c * lin_w[c][.]; k0/k1 = sum of const terms), then each wave
// does the 512-dot for its node. stat/g/be/lw are 8 KB total -> L2-hot.
__global__ __launch_bounds__(256) void final_linear(const unsigned short* __restrict__ xb,
                                                    const float* __restrict__ stat,
                                                    const float* __restrict__ g,
                                                    const float* __restrict__ be,
                                                    const float* __restrict__ lw,
                                                    const float* __restrict__ lb,
                                                    float* __restrict__ out) {
    __shared__ float w01[1024];
    __shared__ float red[512];
    int t = threadIdx.x;
    float rr0 = 0.f, rr1 = 0.f;
#pragma unroll
    for (int q = 0; q < 2; ++q) {
        int c = t * 2 + q; // 0..511
        float mean = stat[c] * (1.0f / NN);
        float var = stat[512 + c] * (1.0f / NN) - mean * mean;
        float sc = g[c] * rsqrtf(var + 1e-5f);
        float sh = be[c] - mean * sc;
        float w0 = lw[2 * c], w1 = lw[2 * c + 1];
        w01[2 * c] = sc * w0;
        w01[2 * c + 1] = sc * w1;
        rr0 = fmaf(sh, w0, rr0);
        rr1 = fmaf(sh, w1, rr1);
    }
    red[t] = rr0;
    red[256 + t] = rr1;
    __syncthreads();
    for (int off = 128; off; off >>= 1) {
        if (t < off) { red[t] += red[t + off]; red[256 + t] += red[256 + t + off]; }
        __syncthreads();
    }
    float k0 = red[0] + lb[0], k1 = red[256] + lb[1];

    int wave = blockIdx.x * 4 + (t >> 6);
    int lane = t & 63;
    short8 hv = *(const short8*)(xb + (size_t)wave * DD + lane * 8);
    float p0 = 0.f, p1 = 0.f;
#pragma unroll
    for (int j = 0; j < 8; ++j) {
        int c = lane * 8 + j;
        float h = bf2f((unsigned short)hv[j]);
        p0 = fmaf(h, w01[2 * c], p0);
        p1 = fmaf(h, w01[2 * c + 1], p1);
    }
    for (int off = 32; off; off >>= 1) {
        p0 += __shfl_down(p0, off);
        p1 += __shfl_down(p1, off);
    }
    if (lane == 0) {
        out[wave * 2 + 0] = fmaxf(p0 + k0, 0.f);
        out[wave * 2 + 1] = fmaxf(p1 + k1, 0.f);
    }
}

extern "C" void kernel_launch(void* const* d_in, const int* in_sizes, int n_in,
                              void* d_out, int out_size, void* d_ws, size_t ws_size,
                              hipStream_t stream) {
    const float* x     = (const float*)d_in[0];
    const void*  ei    = d_in[1];
    const float* W1    = (const float*)d_in[2];
    const float* a1s   = (const float*)d_in[3];
    const float* a1d   = (const float*)d_in[4];
    const float* b1    = (const float*)d_in[5];
    const float* W2    = (const float*)d_in[6];
    const float* a2s   = (const float*)d_in[7];
    const float* a2d   = (const float*)d_in[8];
    const float* b2    = (const float*)d_in[9];
    const float* fc1_w = (const float*)d_in[10];
    const float* fc1_b = (const float*)d_in[11];
    const float* g1    = (const float*)d_in[12];
    const float* be1   = (const float*)d_in[13];
    const float* fc2_w = (const float*)d_in[14];
    const float* fc2_b = (const float*)d_in[15];
    const float* g2    = (const float*)d_in[16];
    const float* be2   = (const float*)d_in[17];
    const float* lin_w = (const float*)d_in[18];
    const float* lin_b = (const float*)d_in[19];
    float* out = (float*)d_out;

    // workspace carve-up (256B aligned)
    char* ws = (char*)d_ws;
    auto alloc = [&](size_t bytes) {
        void* p = (void*)ws;
        ws += (bytes + 255) & ~size_t(255);
        return p;
    };
    unsigned short* h_bf    = (unsigned short*)alloc((size_t)NN * DD * 2); // ping
    unsigned short* act_bf  = (unsigned short*)alloc((size_t)NN * DD * 2); // pong
    unsigned short* W1t     = (unsigned short*)alloc((size_t)DD * FIN * 2);
    unsigned short* fc1t    = (unsigned short*)alloc((size_t)DD * DD * 2);
    unsigned short* W2t     = (unsigned short*)alloc((size_t)DD * DD * 2);
    unsigned short* fc2t    = (unsigned short*)alloc((size_t)DD * DD * 2);
    float*          al_s    = (float*)alloc((size_t)NN * 8 * 4);           // layer-1 logits, HEAD-MAJOR [8][NN]
    float*          al_d    = (float*)alloc((size_t)NN * 8 * 4);
    int*            row_ptr = (int*)alloc((size_t)(NN + 1) * 4);
    int*            perm    = (int*)alloc((size_t)NN * 4);                 // degree-sorted nodes
    float*          bias2f  = (float*)alloc(512 * 4);                      // BN1-fold bias for W2 GEMM
    // zero-region: deg + cursor + bnstatA/B + al_s2 + al_d2 (ONE memset)
    int*            deg     = (int*)alloc((size_t)(4 * NN + 2048) * 4);
    int*            cursor  = deg + NN;
    float*          bnstatA = (float*)(deg + 2 * NN);
    float*          bnstatB = bnstatA + 1024;
    float*          al_s2   = bnstatA + 2048;
    float*          al_d2   = al_s2 + NN;
    // 0xFF-region: csr_srcu (pad slots stay 0xFFFF -> alpha 0 downstream)
    unsigned short* csr_srcu = (unsigned short*)alloc((size_t)ETP_MAX * 2);

    // --- host-side edge dtype detection: in_sizes[1] is byte size of edge_index ---
    const int is64 = (in_sizes[1] >= (int)(2u * EE * 8u)) ? 1 : 0;

    // --- init via graph-capturable async memsets (2 total) ---
    hipMemsetAsync(deg, 0, (size_t)(4 * NN + 2048) * 4, stream);
    hipMemsetAsync(csr_srcu, 0xFF, (size_t)ETP_MAX * 2, stream);

    // --- merged: count_deg + weight transpose + x conversion (one launch) ---
    unsigned short* x_bf = act_bf; // consumed by GEMM1 before gat_gather_k overwrites
    const int prep_blocks = CDB + TBLK + XCB;
    prep_all_k<<<prep_blocks, 256, 0, stream>>>(x, W1, fc1_w, W2, fc2_w,
                                                x_bf, W1t, fc1t, W2t, fc2t,
                                                ei, is64, deg);
    // padded row_ptr + degree-bucketed perm (single block, wave-scan, chain-split atomics)
    scan_k<<<1, 1024, 0, stream>>>(deg, row_ptr, perm);

    const int GB = 640;              // GEMM blocks: 160 padded m-tiles x 4 n-tiles
    const int FB = (ET + 255) / 256; // fused fill_csr blocks (real slots only)
    const int GGB = 8 * (NN / 32);   // gather: 8 col-slices x 625 node-groups = 5000

    // ---------------- Layer 1: GATConv(128 -> 8 x 64) ----------------
    // h1 = x @ W1 (bf16 out) + fused logits (head-major) + fused fill_csr
    gemm_bf16<0, 0, 0, 1, 8, 1><<<GB + FB, 256, 0, stream>>>(
        x_bf, W1t, nullptr, h_bf, nullptr, a1s, a1d, al_s, al_d, NN, DD, FIN,
        ei, is64, row_ptr, cursor, csr_srcu);
    // gather with fused alpha (head == slice; per-slice 80 KB logit plane)
    gat_gather_k<8><<<GGB, 256, 0, stream>>>(h_bf, csr_srcu, al_s, al_d, row_ptr, perm, b1, act_bf);
    // r1 = relu(agg1 @ fc1 + b) (bf16 out) + fused BN stats
    gemm_bf16<1, 1, 1, 0, 8, 0><<<GB, 256, 0, stream>>>(
        act_bf, fc1t, fc1_b, h_bf, bnstatA, nullptr, nullptr, nullptr, nullptr, NN, DD, DD,
        nullptr, 0, nullptr, nullptr, nullptr);
    // fold BN1 into W2 weights + bias
    fold1_k<<<128, 256, 0, stream>>>(bnstatA, g1, be1, W2t, bias2f);

    // ---------------- Layer 2: GATConv(512 -> 1 x 512) ----------------
    // h2 = r1 @ (sc*W2) + (sh@W2) (bf16 out) + fused logits (H=1: atomic into zeroed bufs)
    gemm_bf16<0, 1, 0, 1, 1, 0><<<GB, 256, 0, stream>>>(
        h_bf, W2t, bias2f, act_bf, nullptr, a2s, a2d, al_s2, al_d2, NN, DD, DD,
        nullptr, 0, nullptr, nullptr, nullptr);
    // gather with fused alpha (H=1: exp replicated per slice -- absorbed by idle slots)
    gat_gather_k<1><<<GGB, 256, 0, stream>>>(act_bf, csr_srcu, al_s2, al_d2, row_ptr, perm, b2, h_bf);
    // r2 = relu(agg2 @ fc2 + b) (bf16 out) + fused BN stats
    gemm_bf16<1, 1, 1, 0, 8, 0><<<GB, 256, 0, stream>>>(
        h_bf, fc2t, fc2_b, act_bf, bnstatB, nullptr, nullptr, nullptr, nullptr, NN, DD, DD,
        nullptr, 0, nullptr, nullptr, nullptr);

    // ---------------- head: final linear with BN2 fold fused per-block ----------------
    final_linear<<<NN / 4, 256, 0, stream>>>(act_bf, bnstatB, g2, be2, lin_w, lin_b, out);
}